// Round 1
// baseline (7303.993 us; speedup 1.0000x reference)
//
#include <hip/hip_runtime.h>

#define TXT   512
#define REDUX 64
#define IMG   2048
#define REFN  512
#define ROUTERN 32
#define NC    2
#define SEQ   3168
#define DH    128
#define NH    24
#define TRE   (TXT + REDUX)      // 576
#define TRI   (TXT + REDUX + IMG) // 2624
#define TRIR  (TRI + REFN)        // 3136

#define KT    32                 // key tile
#define LDK   (DH + 4)           // padded LDS stride (16B aligned rows)

__global__ __launch_bounds__(256, 2)
void anystory_attn_kernel(const float* __restrict__ Q, const float* __restrict__ K,
                          const float* __restrict__ V, const float* __restrict__ ref_mask,
                          const float* __restrict__ routing, float* __restrict__ out)
{
    __shared__ float Ks[KT][LDK];
    __shared__ float Vs[KT][LDK];

    const int h    = blockIdx.y;
    const int r0   = blockIdx.x * 4;           // 4 query rows per block (one per wave)
    const int tid  = threadIdx.x;
    const int wave = tid >> 6;
    const int lane = tid & 63;
    const int key_l = lane & 31;               // key slot within tile
    const int half  = lane >> 5;               // which 64-dim half of the dot
    const int row  = r0 + wave;                // this wave's query row

    // ---- key ranges + mask flag, uniform across the block (region boundaries
    //      2624 / 2880 / 3136 are all multiples of 4) ----
    int rs0, re0, rs1 = 0, re1 = 0;
    bool masked = false;
    if (r0 < TRI) {                            // txt/redux/img queries
        rs0 = 0; re0 = TRIR; masked = true;
    } else if (r0 < TRIR) {                    // ref self-attn, per cond
        int c = (r0 - TRI) / (REFN / NC);
        rs0 = TRI + c * (REFN / NC); re0 = rs0 + (REFN / NC);
    } else {                                   // router queries: img keys + router keys
        rs0 = TRE; re0 = TRI; rs1 = TRIR; re1 = SEQ;
    }

    // ---- load this row's q (the 64 dims of this lane's half) into registers ----
    float4 qreg[16];
    const float4* qptr = (const float4*)(Q + ((size_t)h * SEQ + row) * DH + half * 64);
    #pragma unroll
    for (int i = 0; i < 16; ++i) qreg[i] = qptr[i];

    float m = -1e30f, l = 0.f, acc0 = 0.f, acc1 = 0.f;
    const float scale = 0.08838834764831845f;  // 1/sqrt(128)

    for (int range = 0; range < 2; ++range) {
        const int ks = (range == 0) ? rs0 : rs1;
        const int ke = (range == 0) ? re0 : re1;
        for (int kt = ks; kt < ke; kt += KT) {
            __syncthreads();
            // cooperative K/V tile load: 32x128 floats each, float4-vectorized
            #pragma unroll
            for (int i = 0; i < 4; ++i) {
                int idx = tid + i * 256;           // float4 index, 0..1023
                int rr = idx >> 5, cc = (idx & 31) * 4;
                const float4 kv = ((const float4*)(K + ((size_t)h * SEQ + kt + rr) * DH))[idx & 31];
                const float4 vv = ((const float4*)(V + ((size_t)h * SEQ + kt + rr) * DH))[idx & 31];
                *(float4*)&Ks[rr][cc] = kv;
                *(float4*)&Vs[rr][cc] = vv;
            }
            __syncthreads();

            // ---- logits: lanes (key_l, half) each do a 64-dim half-dot ----
            const int kglob = kt + key_l;
            float dot = 0.f;
            #pragma unroll
            for (int i = 0; i < 16; ++i) {
                float4 k4 = *(const float4*)&Ks[key_l][half * 64 + i * 4];
                dot += qreg[i].x * k4.x + qreg[i].y * k4.y + qreg[i].z * k4.z + qreg[i].w * k4.w;
            }
            dot += __shfl_xor(dot, 32);            // combine halves; both halves hold full dot
            float logit = dot * scale;

            if (masked) {
                if (kglob >= TRI) {                // ref keys: shift + ref_mask (+ routing for img q)
                    logit += 1.5f + (ref_mask[(size_t)(kglob - TRI) * TRI + row] - 1.f) * 100.f;
                    if (row >= TRE)
                        logit += (routing[((kglob - TRI) >> 8) * IMG + (row - TRE)] - 1.f) * 100.f;
                } else if (kglob >= TXT && kglob < TRE && row >= TRE) {  // redux keys, img queries
                    logit += (routing[((kglob - TXT) >> 5) * IMG + (row - TRE)] - 1.f) * 100.f;
                }
            }

            // ---- online softmax (32 keys; values duplicated across the two halves) ----
            float tm = logit;
            tm = fmaxf(tm, __shfl_xor(tm, 1));
            tm = fmaxf(tm, __shfl_xor(tm, 2));
            tm = fmaxf(tm, __shfl_xor(tm, 4));
            tm = fmaxf(tm, __shfl_xor(tm, 8));
            tm = fmaxf(tm, __shfl_xor(tm, 16));
            const float nm   = fmaxf(m, tm);
            const float corr = __expf(m - nm);
            const float p    = __expf(logit - nm);
            float ps = p;
            ps += __shfl_xor(ps, 1);
            ps += __shfl_xor(ps, 2);
            ps += __shfl_xor(ps, 4);
            ps += __shfl_xor(ps, 8);
            ps += __shfl_xor(ps, 16);
            l = l * corr + ps;
            acc0 *= corr; acc1 *= corr;
            m = nm;

            // ---- PV: each lane owns output dims {lane, lane+64} ----
            #pragma unroll
            for (int k = 0; k < KT; ++k) {
                const float pk = __shfl(p, k);     // key k's prob lives in lane k
                acc0 += pk * Vs[k][lane];
                acc1 += pk * Vs[k][lane + 64];
            }
        }
    }

    const float inv = 1.f / l;
    float* op = out + ((size_t)h * SEQ + row) * DH;
    op[lane]      = acc0 * inv;
    op[lane + 64] = acc1 * inv;
}

extern "C" void kernel_launch(void* const* d_in, const int* in_sizes, int n_in,
                              void* d_out, int out_size, void* d_ws, size_t ws_size,
                              hipStream_t stream) {
    const float* Q        = (const float*)d_in[0];
    const float* K        = (const float*)d_in[1];
    const float* V        = (const float*)d_in[2];
    const float* ref_mask = (const float*)d_in[3];
    const float* routing  = (const float*)d_in[4];
    float* out = (float*)d_out;

    dim3 grid(SEQ / 4, NH);
    anystory_attn_kernel<<<grid, 256, 0, stream>>>(Q, K, V, ref_mask, routing, out);
}

// Round 2
// 603.404 us; speedup vs baseline: 12.1046x; 12.1046x over previous
//
#include <hip/hip_runtime.h>
#include <hip/hip_bf16.h>

#define TXT   512
#define REDUX 64
#define IMG   2048
#define REFN  512
#define NC    2
#define SEQ   3168
#define DH    128
#define NH    24
#define TRE   576
#define TRI   2624
#define TRIR  3136
#define SCALE 0.08838834764831845f

using f32x4  = __attribute__((ext_vector_type(4))) float;
using short8 = __attribute__((ext_vector_type(8))) short;

__device__ inline short f2bf(float x) {
    union { __hip_bfloat16 b; short s; } u;
    u.b = __float2bfloat16(x);
    return u.s;
}

// ---------------- pre-pass 1: K f32 -> bf16 linear ----------------
__global__ void cvt_k_kernel(const float* __restrict__ K, short* __restrict__ Kb) {
    const int i = blockIdx.x * 256 + threadIdx.x;      // one float4 per thread
    const float4 v = ((const float4*)K)[i];
    short4 o;
    o.x = f2bf(v.x); o.y = f2bf(v.y); o.z = f2bf(v.z); o.w = f2bf(v.w);
    ((short4*)Kb)[i] = o;
}

// ---------------- pre-pass 2: V f32 -> bf16 transposed Vt[h][d][s] ----------------
__global__ void cvt_v_kernel(const float* __restrict__ V, short* __restrict__ Vt) {
    const int h  = blockIdx.y;
    const int s8 = blockIdx.x * 2 + (threadIdx.x >> 7);   // 0..395
    const int d  = threadIdx.x & 127;
    const int s0 = s8 * 8;
    const float* src = V + ((size_t)h * SEQ + s0) * DH + d;
    short8 w;
    #pragma unroll
    for (int j = 0; j < 8; ++j) w[j] = f2bf(src[j * DH]);
    short* dst = Vt + ((size_t)h * DH + d) * SEQ + s0;
    *(short8*)dst = w;
}

// ---------------- MFMA flash attention: regions 1 (masked) + 2 (ref self) ----------------
__global__ __launch_bounds__(256, 2)
void attn_mfma(const float* __restrict__ Q, const short* __restrict__ Kb,
               const short* __restrict__ Vtg, const float* __restrict__ ref_mask,
               const float* __restrict__ routing, float* __restrict__ out)
{
    __shared__ short Ks[64 * 128];     // [key][d] bf16, swizzled
    __shared__ short Vs[128 * 64];     // [d][key] bf16, swizzled
    __shared__ short Pl[4][32 * 64];   // per-wave P, swizzled

    const int h    = blockIdx.y;
    const int bx   = blockIdx.x;
    const int tid  = threadIdx.x;
    const int wave = tid >> 6, lane = tid & 63;
    const int g    = lane >> 4, l4 = lane & 15;

    int qbase, ks0, ntiles;
    bool masked;
    if (bx < 21) { qbase = bx * 128; ks0 = 0; ntiles = 49; masked = true; }
    else {
        const int b2 = bx - 21;
        qbase = TRI + b2 * 128;
        ks0 = TRI + (b2 >> 1) * 256; ntiles = 4; masked = false;
    }

    const int rbase = qbase + wave * 32;
    const bool valid = !(bx < 21 && rbase >= TRI);

    // ---- Q fragments (pre-scaled, bf16): qA[qt][ks], row = l4, k = g*8+i ----
    short8 qA[2][4];
    if (valid) {
        #pragma unroll
        for (int qt = 0; qt < 2; ++qt) {
            const int q = rbase + qt * 16 + l4;
            const float* qp = Q + ((size_t)h * SEQ + q) * DH;
            #pragma unroll
            for (int ks = 0; ks < 4; ++ks) {
                const float4 a = *(const float4*)(qp + ks * 32 + g * 8);
                const float4 b = *(const float4*)(qp + ks * 32 + g * 8 + 4);
                short8 f;
                f[0] = f2bf(a.x * SCALE); f[1] = f2bf(a.y * SCALE);
                f[2] = f2bf(a.z * SCALE); f[3] = f2bf(a.w * SCALE);
                f[4] = f2bf(b.x * SCALE); f[5] = f2bf(b.y * SCALE);
                f[6] = f2bf(b.z * SCALE); f[7] = f2bf(b.w * SCALE);
                qA[qt][ks] = f;
            }
        }
    }

    f32x4 acc[2][8] = {};
    f32x4 m_run[2], l_run[2];
    #pragma unroll
    for (int qt = 0; qt < 2; ++qt) {
        #pragma unroll
        for (int r = 0; r < 4; ++r) { m_run[qt][r] = -3.0e38f; l_run[qt][r] = 0.f; }
    }

    for (int t = 0; t < ntiles; ++t) {
        const int kt = ks0 + t * 64;
        __syncthreads();
        // ---- stage K tile (64 keys x 128 d), swizzle ^(key&7) on 16B chunks ----
        #pragma unroll
        for (int i = 0; i < 4; ++i) {
            const int idx = tid + i * 256;
            const int key = idx >> 4, c = idx & 15;
            const short8 kv = *(const short8*)(Kb + ((size_t)h * SEQ + kt + key) * DH + c * 8);
            *(short8*)(Ks + key * 128 + ((c ^ (key & 7)) << 3)) = kv;
        }
        // ---- stage V tile transposed (128 d x 64 keys), swizzle ^((d>>2)&7) ----
        #pragma unroll
        for (int i = 0; i < 4; ++i) {
            const int idx = tid + i * 256;
            const int d = idx >> 3, kc = idx & 7;
            const short8 vv = *(const short8*)(Vtg + ((size_t)h * DH + d) * SEQ + kt + kc * 8);
            *(short8*)(Vs + d * 64 + ((kc ^ ((d >> 2) & 7)) << 3)) = vv;
        }
        __syncthreads();

        if (!valid) continue;

        // ---- QK^T: s[qt][nt] = Q(16x128) . K^T(128x16nt) ----
        f32x4 s[2][4] = {};
        #pragma unroll
        for (int nt = 0; nt < 4; ++nt) {
            const int key = nt * 16 + l4;
            short8 kB[4];
            #pragma unroll
            for (int ks = 0; ks < 4; ++ks)
                kB[ks] = *(const short8*)(Ks + key * 128 + (((ks * 4 + g) ^ (key & 7)) << 3));
            #pragma unroll
            for (int qt = 0; qt < 2; ++qt)
                #pragma unroll
                for (int ks = 0; ks < 4; ++ks)
                    s[qt][nt] = __builtin_amdgcn_mfma_f32_16x16x32_bf16(qA[qt][ks], kB[ks], s[qt][nt], 0, 0, 0);
        }

        // ---- masks (f32, exact) ----
        if (masked) {
            if (kt >= TRI) {                       // ref-key tiles
                const int cr = (kt - TRI) >> 8;
                #pragma unroll
                for (int qt = 0; qt < 2; ++qt) {
                    const int q0 = rbase + qt * 16 + g * 4;
                    const bool hr = (rbase + qt * 16) >= TRE;
                    f32x4 rt = {};
                    if (hr) rt = *(const f32x4*)(routing + cr * IMG + (q0 - TRE));
                    #pragma unroll
                    for (int nt = 0; nt < 4; ++nt) {
                        const int j = kt - TRI + nt * 16 + l4;
                        const f32x4 rm = *(const f32x4*)(ref_mask + (size_t)j * TRI + q0);
                        #pragma unroll
                        for (int r = 0; r < 4; ++r) {
                            float add = rm[r] * 100.f - 98.5f;   // 1.5 + (rm-1)*100
                            if (hr) add += (rt[r] - 1.f) * 100.f;
                            s[qt][nt][r] += add;
                        }
                    }
                }
            } else if (kt == TXT) {                // redux-key tile (keys 512..575)
                #pragma unroll
                for (int qt = 0; qt < 2; ++qt) {
                    if ((rbase + qt * 16) >= TRE) {
                        const int q0 = rbase + qt * 16 + g * 4;
                        const f32x4 rt0 = *(const f32x4*)(routing + (q0 - TRE));
                        const f32x4 rt1 = *(const f32x4*)(routing + IMG + (q0 - TRE));
                        #pragma unroll
                        for (int nt = 0; nt < 4; ++nt)
                            #pragma unroll
                            for (int r = 0; r < 4; ++r)
                                s[qt][nt][r] += (((nt >> 1) ? rt1[r] : rt0[r]) - 1.f) * 100.f;
                    }
                }
            }
        }

        // ---- online softmax + P write ----
        #pragma unroll
        for (int qt = 0; qt < 2; ++qt) {
            f32x4 mx = s[qt][0];
            #pragma unroll
            for (int nt = 1; nt < 4; ++nt)
                #pragma unroll
                for (int r = 0; r < 4; ++r) mx[r] = fmaxf(mx[r], s[qt][nt][r]);
            #pragma unroll
            for (int dd = 1; dd < 16; dd <<= 1)
                #pragma unroll
                for (int r = 0; r < 4; ++r) mx[r] = fmaxf(mx[r], __shfl_xor(mx[r], dd));

            f32x4 mnew, corr, rs;
            #pragma unroll
            for (int r = 0; r < 4; ++r) {
                mnew[r] = fmaxf(m_run[qt][r], mx[r]);
                corr[r] = __expf(m_run[qt][r] - mnew[r]);
                rs[r] = 0.f;
            }
            #pragma unroll
            for (int nt = 0; nt < 4; ++nt)
                #pragma unroll
                for (int r = 0; r < 4; ++r) {
                    s[qt][nt][r] = __expf(s[qt][nt][r] - mnew[r]);
                    rs[r] += s[qt][nt][r];
                }
            #pragma unroll
            for (int dd = 1; dd < 16; dd <<= 1)
                #pragma unroll
                for (int r = 0; r < 4; ++r) rs[r] += __shfl_xor(rs[r], dd);
            #pragma unroll
            for (int r = 0; r < 4; ++r) {
                l_run[qt][r] = l_run[qt][r] * corr[r] + rs[r];
                m_run[qt][r] = mnew[r];
            }
            #pragma unroll
            for (int nt = 0; nt < 8; ++nt)
                #pragma unroll
                for (int r = 0; r < 4; ++r) acc[qt][nt][r] *= corr[r];
            // write P (C/D layout -> swizzled LDS)
            #pragma unroll
            for (int nt = 0; nt < 4; ++nt)
                #pragma unroll
                for (int r = 0; r < 4; ++r) {
                    const int row = qt * 16 + g * 4 + r;
                    const int col = nt * 16 + l4;
                    Pl[wave][row * 64 + (col ^ ((row & 7) << 3))] = f2bf(s[qt][nt][r]);
                }
        }

        // ---- PV: acc[qt][nt] += P(16x32ks) . V(32ks x 16nt) ----
        #pragma unroll
        for (int ks2 = 0; ks2 < 2; ++ks2) {
            short8 pA[2];
            #pragma unroll
            for (int qt = 0; qt < 2; ++qt) {
                const int row = qt * 16 + l4;
                pA[qt] = *(const short8*)(&Pl[wave][row * 64 + ((((ks2 * 4 + g)) ^ (row & 7)) << 3)]);
            }
            #pragma unroll
            for (int nt = 0; nt < 8; ++nt) {
                const int d = nt * 16 + l4;
                const short8 vB = *(const short8*)(Vs + d * 64 + (((ks2 * 4 + g) ^ ((d >> 2) & 7)) << 3));
                #pragma unroll
                for (int qt = 0; qt < 2; ++qt)
                    acc[qt][nt] = __builtin_amdgcn_mfma_f32_16x16x32_bf16(pA[qt], vB, acc[qt][nt], 0, 0, 0);
            }
        }
    }

    if (valid) {
        #pragma unroll
        for (int qt = 0; qt < 2; ++qt) {
            #pragma unroll
            for (int nt = 0; nt < 8; ++nt)
                #pragma unroll
                for (int r = 0; r < 4; ++r) {
                    const int q = rbase + qt * 16 + g * 4 + r;
                    out[((size_t)h * SEQ + q) * DH + nt * 16 + l4] = acc[qt][nt][r] / l_run[qt][r];
                }
        }
    }
}

// ---------------- scalar kernel (router region + full fallback) ----------------
#define KT  32
#define LDK (DH + 4)
__global__ __launch_bounds__(256, 2)
void anystory_attn_scalar(const float* __restrict__ Q, const float* __restrict__ K,
                          const float* __restrict__ V, const float* __restrict__ ref_mask,
                          const float* __restrict__ routing, float* __restrict__ out, int row0)
{
    __shared__ float KsS[KT][LDK];
    __shared__ float VsS[KT][LDK];

    const int h    = blockIdx.y;
    const int r0   = row0 + blockIdx.x * 4;
    const int tid  = threadIdx.x;
    const int wave = tid >> 6;
    const int lane = tid & 63;
    const int key_l = lane & 31;
    const int half  = lane >> 5;
    const int row  = r0 + wave;

    int rs0, re0, rs1 = 0, re1 = 0;
    bool masked = false;
    if (r0 < TRI) { rs0 = 0; re0 = TRIR; masked = true; }
    else if (r0 < TRIR) {
        int c = (r0 - TRI) / (REFN / NC);
        rs0 = TRI + c * (REFN / NC); re0 = rs0 + (REFN / NC);
    } else { rs0 = TRE; re0 = TRI; rs1 = TRIR; re1 = SEQ; }

    float4 qreg[16];
    const float4* qptr = (const float4*)(Q + ((size_t)h * SEQ + row) * DH + half * 64);
    #pragma unroll
    for (int i = 0; i < 16; ++i) qreg[i] = qptr[i];

    float m = -1e30f, l = 0.f, acc0 = 0.f, acc1 = 0.f;

    for (int range = 0; range < 2; ++range) {
        const int ks = (range == 0) ? rs0 : rs1;
        const int ke = (range == 0) ? re0 : re1;
        for (int kt = ks; kt < ke; kt += KT) {
            __syncthreads();
            #pragma unroll
            for (int i = 0; i < 4; ++i) {
                int idx = tid + i * 256;
                int rr = idx >> 5, cc = (idx & 31) * 4;
                const float4 kv = ((const float4*)(K + ((size_t)h * SEQ + kt + rr) * DH))[idx & 31];
                const float4 vv = ((const float4*)(V + ((size_t)h * SEQ + kt + rr) * DH))[idx & 31];
                *(float4*)&KsS[rr][cc] = kv;
                *(float4*)&VsS[rr][cc] = vv;
            }
            __syncthreads();

            const int kglob = kt + key_l;
            float dot = 0.f;
            #pragma unroll
            for (int i = 0; i < 16; ++i) {
                float4 k4 = *(const float4*)&KsS[key_l][half * 64 + i * 4];
                dot += qreg[i].x * k4.x + qreg[i].y * k4.y + qreg[i].z * k4.z + qreg[i].w * k4.w;
            }
            dot += __shfl_xor(dot, 32);
            float logit = dot * SCALE;

            if (masked) {
                if (kglob >= TRI) {
                    logit += 1.5f + (ref_mask[(size_t)(kglob - TRI) * TRI + row] - 1.f) * 100.f;
                    if (row >= TRE)
                        logit += (routing[((kglob - TRI) >> 8) * IMG + (row - TRE)] - 1.f) * 100.f;
                } else if (kglob >= TXT && kglob < TRE && row >= TRE) {
                    logit += (routing[((kglob - TXT) >> 5) * IMG + (row - TRE)] - 1.f) * 100.f;
                }
            }

            float tm = logit;
            tm = fmaxf(tm, __shfl_xor(tm, 1));
            tm = fmaxf(tm, __shfl_xor(tm, 2));
            tm = fmaxf(tm, __shfl_xor(tm, 4));
            tm = fmaxf(tm, __shfl_xor(tm, 8));
            tm = fmaxf(tm, __shfl_xor(tm, 16));
            const float nm   = fmaxf(m, tm);
            const float corr = __expf(m - nm);
            const float p    = __expf(logit - nm);
            float ps = p;
            ps += __shfl_xor(ps, 1);
            ps += __shfl_xor(ps, 2);
            ps += __shfl_xor(ps, 4);
            ps += __shfl_xor(ps, 8);
            ps += __shfl_xor(ps, 16);
            l = l * corr + ps;
            acc0 *= corr; acc1 *= corr;
            m = nm;

            #pragma unroll
            for (int k = 0; k < KT; ++k) {
                const float pk = __shfl(p, k);
                acc0 += pk * VsS[k][lane];
                acc1 += pk * VsS[k][lane + 64];
            }
        }
    }

    const float inv = 1.f / l;
    float* op = out + ((size_t)h * SEQ + row) * DH;
    op[lane]      = acc0 * inv;
    op[lane + 64] = acc1 * inv;
}

extern "C" void kernel_launch(void* const* d_in, const int* in_sizes, int n_in,
                              void* d_out, int out_size, void* d_ws, size_t ws_size,
                              hipStream_t stream) {
    const float* Q        = (const float*)d_in[0];
    const float* K        = (const float*)d_in[1];
    const float* V        = (const float*)d_in[2];
    const float* ref_mask = (const float*)d_in[3];
    const float* routing  = (const float*)d_in[4];
    float* out = (float*)d_out;

    const size_t elems = (size_t)NH * SEQ * DH;            // 9,732,096
    const size_t need  = 2 * elems * sizeof(short);        // 38,928,384 B

    if (ws_size < need) {
        // fallback: verified scalar kernel over all rows
        dim3 grid(SEQ / 4, NH);
        anystory_attn_scalar<<<grid, 256, 0, stream>>>(Q, K, V, ref_mask, routing, out, 0);
        return;
    }

    short* Kb  = (short*)d_ws;
    short* Vtg = Kb + elems;

    cvt_k_kernel<<<(int)(elems / 4 / 256), 256, 0, stream>>>(K, Kb);
    cvt_v_kernel<<<dim3(198, NH), 256, 0, stream>>>(V, Vtg);

    attn_mfma<<<dim3(25, NH), 256, 0, stream>>>(Q, Kb, Vtg, ref_mask, routing, out);

    // region 3 (router rows 3136..3167) via scalar kernel
    anystory_attn_scalar<<<dim3(8, NH), 256, 0, stream>>>(Q, K, V, ref_mask, routing, out, TRIR);
}

// Round 3
// 375.999 us; speedup vs baseline: 19.4256x; 1.6048x over previous
//
#include <hip/hip_runtime.h>
#include <hip/hip_bf16.h>

#define TXT   512
#define REDUX 64
#define IMG   2048
#define REFN  512
#define NC    2
#define SEQ   3168
#define DH    128
#define NH    24
#define TRE   576
#define TRI   2624
#define TRIR  3136
#define SCALE 0.08838834764831845f
#define DEFER_THR 4.0f

using f32x4  = __attribute__((ext_vector_type(4))) float;
using short8 = __attribute__((ext_vector_type(8))) short;

__device__ inline short f2bf(float x) {
    union { __hip_bfloat16 b; short s; } u;
    u.b = __float2bfloat16(x);
    return u.s;
}

__device__ inline void gload16(const short* g, short* l) {
    __builtin_amdgcn_global_load_lds(
        (const __attribute__((address_space(1))) unsigned int*)g,
        (__attribute__((address_space(3))) unsigned int*)l, 16, 0, 0);
}

// ---------------- pre-pass 1: K f32 -> bf16 linear ----------------
__global__ void cvt_k_kernel(const float* __restrict__ K, short* __restrict__ Kb) {
    const int i = blockIdx.x * 256 + threadIdx.x;
    const float4 v = ((const float4*)K)[i];
    short4 o;
    o.x = f2bf(v.x); o.y = f2bf(v.y); o.z = f2bf(v.z); o.w = f2bf(v.w);
    ((short4*)Kb)[i] = o;
}

// ---------------- pre-pass 2: V f32 -> bf16 transposed Vt[h][d][s] ----------------
__global__ void cvt_v_kernel(const float* __restrict__ V, short* __restrict__ Vt) {
    const int h  = blockIdx.y;
    const int s8 = blockIdx.x * 2 + (threadIdx.x >> 7);
    const int d  = threadIdx.x & 127;
    const int s0 = s8 * 8;
    const float* src = V + ((size_t)h * SEQ + s0) * DH + d;
    short8 w;
    #pragma unroll
    for (int j = 0; j < 8; ++j) w[j] = f2bf(src[j * DH]);
    short* dst = Vt + ((size_t)h * DH + d) * SEQ + s0;
    *(short8*)dst = w;
}

// ---------------- MFMA flash attention: regions 1 (masked) + 2 (ref self) ----------------
__global__ __launch_bounds__(512, 4)
void attn_mfma(const float* __restrict__ Q, const short* __restrict__ Kb,
               const short* __restrict__ Vtg, const float* __restrict__ ref_mask,
               const float* __restrict__ routing, float* __restrict__ out)
{
    __shared__ short Ks[64 * 128];     // [key][chunk^(key&7)] bf16
    __shared__ short Vs[128 * 64];     // [d][kc^(d&7)] bf16
    __shared__ short Pl[8][16 * 64];   // per-wave P, swizzled

    const int h    = blockIdx.x;
    const int bx   = blockIdx.y;
    const int tid  = threadIdx.x;
    const int wave = tid >> 6, lane = tid & 63;
    const int g    = lane >> 4, l4 = lane & 15;

    int qbase, ks0, ntiles;
    bool masked;
    if (bx < 21) { qbase = bx * 128; ks0 = 0; ntiles = 49; masked = true; }
    else {
        const int b2 = bx - 21;
        qbase = TRI + b2 * 128;
        ks0 = TRI + (b2 >> 1) * 256; ntiles = 4; masked = false;
    }

    const int rbase = qbase + wave * 16;                 // this wave's 16 q rows
    const bool valid = !(masked && rbase >= TRI);

    // ---- staging address precompute (pre-swizzled global source, linear LDS dest) ----
    const short* KbH = Kb  + (size_t)h * SEQ * DH;
    const short* VtH = Vtg + (size_t)h * DH * SEQ;
    const int ci0 = tid, ci1 = tid + 512;
    const int kkey0 = ci0 >> 4, kc0 = ci0 & 15;
    const int kkey1 = ci1 >> 4, kc1 = ci1 & 15;
    const int koff0 = kkey0 * 128 + ((kc0 ^ (kkey0 & 7)) << 3);
    const int koff1 = kkey1 * 128 + ((kc1 ^ (kkey1 & 7)) << 3);
    const int vd0 = ci0 >> 3, vkc0 = ci0 & 7;
    const int vd1 = ci1 >> 3, vkc1 = ci1 & 7;
    const int voff0 = vd0 * SEQ + ((vkc0 ^ (vd0 & 7)) << 3);
    const int voff1 = vd1 * SEQ + ((vkc1 ^ (vd1 & 7)) << 3);
    short* ksdst0 = Ks + (size_t)(wave * 64) * 8;
    short* ksdst1 = Ks + (size_t)(512 + wave * 64) * 8;
    short* vsdst0 = Vs + (size_t)(wave * 64) * 8;
    short* vsdst1 = Vs + (size_t)(512 + wave * 64) * 8;

    // ---- Q fragments (pre-scaled bf16): row = l4, k-chunk = ks*4+g ----
    short8 qA[4];
    if (valid) {
        const int q = rbase + l4;
        const float* qp = Q + ((size_t)h * SEQ + q) * DH;
        #pragma unroll
        for (int ks = 0; ks < 4; ++ks) {
            const float4 a = *(const float4*)(qp + ks * 32 + g * 8);
            const float4 b = *(const float4*)(qp + ks * 32 + g * 8 + 4);
            short8 f;
            f[0] = f2bf(a.x * SCALE); f[1] = f2bf(a.y * SCALE);
            f[2] = f2bf(a.z * SCALE); f[3] = f2bf(a.w * SCALE);
            f[4] = f2bf(b.x * SCALE); f[5] = f2bf(b.y * SCALE);
            f[6] = f2bf(b.z * SCALE); f[7] = f2bf(b.w * SCALE);
            qA[ks] = f;
        }
    }

    f32x4 acc[8] = {};
    f32x4 m_run, l_run;
    #pragma unroll
    for (int r = 0; r < 4; ++r) { m_run[r] = -3.0e38f; l_run[r] = 0.f; }

    for (int t = 0; t < ntiles; ++t) {
        const int kt = ks0 + t * 64;
        __syncthreads();                                   // previous tile consumed
        const short* kbase = KbH + (size_t)kt * DH;
        const short* vbase = VtH + kt;
        gload16(kbase + koff0, ksdst0);
        gload16(kbase + koff1, ksdst1);
        gload16(vbase + voff0, vsdst0);
        gload16(vbase + voff1, vsdst1);
        __syncthreads();                                   // drains vmcnt + barrier

        if (!valid) continue;

        // ---- QK^T ----
        f32x4 s[4] = {};
        __builtin_amdgcn_s_setprio(1);
        #pragma unroll
        for (int nt = 0; nt < 4; ++nt) {
            const int key = nt * 16 + l4;
            #pragma unroll
            for (int ks = 0; ks < 4; ++ks) {
                const short8 kB = *(const short8*)(Ks + key * 128 + (((ks * 4 + g) ^ (key & 7)) << 3));
                s[nt] = __builtin_amdgcn_mfma_f32_16x16x32_bf16(qA[ks], kB, s[nt], 0, 0, 0);
            }
        }
        __builtin_amdgcn_s_setprio(0);

        // ---- masks (f32, exact) ----
        if (masked) {
            if (kt >= TRI) {                               // ref-key tiles
                const int cr = (kt - TRI) >> 8;
                const int q0 = rbase + g * 4;
                const bool hr = rbase >= TRE;
                f32x4 rt = {};
                if (hr) rt = *(const f32x4*)(routing + cr * IMG + (q0 - TRE));
                #pragma unroll
                for (int nt = 0; nt < 4; ++nt) {
                    const int j = kt - TRI + nt * 16 + l4;
                    const f32x4 rm = *(const f32x4*)(ref_mask + (size_t)j * TRI + q0);
                    #pragma unroll
                    for (int r = 0; r < 4; ++r) {
                        float add = rm[r] * 100.f - 98.5f;   // 1.5 + (rm-1)*100
                        if (hr) add += (rt[r] - 1.f) * 100.f;
                        s[nt][r] += add;
                    }
                }
            } else if (kt == TXT) {                        // redux-key tile
                if (rbase >= TRE) {
                    const int q0 = rbase + g * 4;
                    const f32x4 rt0 = *(const f32x4*)(routing + (q0 - TRE));
                    const f32x4 rt1 = *(const f32x4*)(routing + IMG + (q0 - TRE));
                    #pragma unroll
                    for (int nt = 0; nt < 4; ++nt)
                        #pragma unroll
                        for (int r = 0; r < 4; ++r)
                            s[nt][r] += (((nt >> 1) ? rt1[r] : rt0[r]) - 1.f) * 100.f;
                }
            }
        }

        // ---- online softmax with defer-max ----
        f32x4 mx = s[0];
        #pragma unroll
        for (int nt = 1; nt < 4; ++nt)
            #pragma unroll
            for (int r = 0; r < 4; ++r) mx[r] = fmaxf(mx[r], s[nt][r]);
        #pragma unroll
        for (int dd = 1; dd < 16; dd <<= 1)
            #pragma unroll
            for (int r = 0; r < 4; ++r) mx[r] = fmaxf(mx[r], __shfl_xor(mx[r], dd));

        float gmax = fmaxf(fmaxf(mx[0] - m_run[0], mx[1] - m_run[1]),
                           fmaxf(mx[2] - m_run[2], mx[3] - m_run[3]));
        if (__any(gmax > DEFER_THR)) {
            f32x4 corr;
            #pragma unroll
            for (int r = 0; r < 4; ++r) {
                const float mn = fmaxf(m_run[r], mx[r]);
                corr[r] = __expf(m_run[r] - mn);
                m_run[r] = mn;
                l_run[r] *= corr[r];
            }
            #pragma unroll
            for (int nt = 0; nt < 8; ++nt)
                #pragma unroll
                for (int r = 0; r < 4; ++r) acc[nt][r] *= corr[r];
        }

        f32x4 rs = {};
        #pragma unroll
        for (int nt = 0; nt < 4; ++nt)
            #pragma unroll
            for (int r = 0; r < 4; ++r) {
                s[nt][r] = __expf(s[nt][r] - m_run[r]);
                rs[r] += s[nt][r];
            }
        #pragma unroll
        for (int dd = 1; dd < 16; dd <<= 1)
            #pragma unroll
            for (int r = 0; r < 4; ++r) rs[r] += __shfl_xor(rs[r], dd);
        #pragma unroll
        for (int r = 0; r < 4; ++r) l_run[r] += rs[r];

        // ---- P (C/D layout) -> swizzled LDS ----
        #pragma unroll
        for (int nt = 0; nt < 4; ++nt)
            #pragma unroll
            for (int r = 0; r < 4; ++r) {
                const int row = g * 4 + r;
                const int col = nt * 16 + l4;
                Pl[wave][row * 64 + (col ^ ((row & 7) << 3))] = f2bf(s[nt][r]);
            }

        // ---- PV ----
        __builtin_amdgcn_s_setprio(1);
        #pragma unroll
        for (int ks2 = 0; ks2 < 2; ++ks2) {
            const short8 pA = *(const short8*)(&Pl[wave][l4 * 64 + (((ks2 * 4 + g) ^ (l4 & 7)) << 3)]);
            #pragma unroll
            for (int nt = 0; nt < 8; ++nt) {
                const int d = nt * 16 + l4;
                const short8 vB = *(const short8*)(Vs + d * 64 + (((ks2 * 4 + g) ^ (d & 7)) << 3));
                acc[nt] = __builtin_amdgcn_mfma_f32_16x16x32_bf16(pA, vB, acc[nt], 0, 0, 0);
            }
        }
        __builtin_amdgcn_s_setprio(0);
    }

    if (valid) {
        #pragma unroll
        for (int nt = 0; nt < 8; ++nt)
            #pragma unroll
            for (int r = 0; r < 4; ++r) {
                const int q = rbase + g * 4 + r;
                out[((size_t)h * SEQ + q) * DH + nt * 16 + l4] = acc[nt][r] / l_run[r];
            }
    }
}

// ---------------- scalar kernel (router region + full fallback) ----------------
#define KT  32
#define LDK (DH + 4)
__global__ __launch_bounds__(256, 2)
void anystory_attn_scalar(const float* __restrict__ Q, const float* __restrict__ K,
                          const float* __restrict__ V, const float* __restrict__ ref_mask,
                          const float* __restrict__ routing, float* __restrict__ out, int row0)
{
    __shared__ float KsS[KT][LDK];
    __shared__ float VsS[KT][LDK];

    const int h    = blockIdx.y;
    const int r0   = row0 + blockIdx.x * 4;
    const int tid  = threadIdx.x;
    const int wave = tid >> 6;
    const int lane = tid & 63;
    const int key_l = lane & 31;
    const int half  = lane >> 5;
    const int row  = r0 + wave;

    int rs0, re0, rs1 = 0, re1 = 0;
    bool masked = false;
    if (r0 < TRI) { rs0 = 0; re0 = TRIR; masked = true; }
    else if (r0 < TRIR) {
        int c = (r0 - TRI) / (REFN / NC);
        rs0 = TRI + c * (REFN / NC); re0 = rs0 + (REFN / NC);
    } else { rs0 = TRE; re0 = TRI; rs1 = TRIR; re1 = SEQ; }

    float4 qreg[16];
    const float4* qptr = (const float4*)(Q + ((size_t)h * SEQ + row) * DH + half * 64);
    #pragma unroll
    for (int i = 0; i < 16; ++i) qreg[i] = qptr[i];

    float m = -1e30f, l = 0.f, acc0 = 0.f, acc1 = 0.f;

    for (int range = 0; range < 2; ++range) {
        const int ks = (range == 0) ? rs0 : rs1;
        const int ke = (range == 0) ? re0 : re1;
        for (int kt = ks; kt < ke; kt += KT) {
            __syncthreads();
            #pragma unroll
            for (int i = 0; i < 4; ++i) {
                int idx = tid + i * 256;
                int rr = idx >> 5, cc = (idx & 31) * 4;
                const float4 kv = ((const float4*)(K + ((size_t)h * SEQ + kt + rr) * DH))[idx & 31];
                const float4 vv = ((const float4*)(V + ((size_t)h * SEQ + kt + rr) * DH))[idx & 31];
                *(float4*)&KsS[rr][cc] = kv;
                *(float4*)&VsS[rr][cc] = vv;
            }
            __syncthreads();

            const int kglob = kt + key_l;
            float dot = 0.f;
            #pragma unroll
            for (int i = 0; i < 16; ++i) {
                float4 k4 = *(const float4*)&KsS[key_l][half * 64 + i * 4];
                dot += qreg[i].x * k4.x + qreg[i].y * k4.y + qreg[i].z * k4.z + qreg[i].w * k4.w;
            }
            dot += __shfl_xor(dot, 32);
            float logit = dot * SCALE;

            if (masked) {
                if (kglob >= TRI) {
                    logit += 1.5f + (ref_mask[(size_t)(kglob - TRI) * TRI + row] - 1.f) * 100.f;
                    if (row >= TRE)
                        logit += (routing[((kglob - TRI) >> 8) * IMG + (row - TRE)] - 1.f) * 100.f;
                } else if (kglob >= TXT && kglob < TRE && row >= TRE) {
                    logit += (routing[((kglob - TXT) >> 5) * IMG + (row - TRE)] - 1.f) * 100.f;
                }
            }

            float tm = logit;
            tm = fmaxf(tm, __shfl_xor(tm, 1));
            tm = fmaxf(tm, __shfl_xor(tm, 2));
            tm = fmaxf(tm, __shfl_xor(tm, 4));
            tm = fmaxf(tm, __shfl_xor(tm, 8));
            tm = fmaxf(tm, __shfl_xor(tm, 16));
            const float nm   = fmaxf(m, tm);
            const float corr = __expf(m - nm);
            const float p    = __expf(logit - nm);
            float ps = p;
            ps += __shfl_xor(ps, 1);
            ps += __shfl_xor(ps, 2);
            ps += __shfl_xor(ps, 4);
            ps += __shfl_xor(ps, 8);
            ps += __shfl_xor(ps, 16);
            l = l * corr + ps;
            acc0 *= corr; acc1 *= corr;
            m = nm;

            #pragma unroll
            for (int k = 0; k < KT; ++k) {
                const float pk = __shfl(p, k);
                acc0 += pk * VsS[k][lane];
                acc1 += pk * VsS[k][lane + 64];
            }
        }
    }

    const float inv = 1.f / l;
    float* op = out + ((size_t)h * SEQ + row) * DH;
    op[lane]      = acc0 * inv;
    op[lane + 64] = acc1 * inv;
}

extern "C" void kernel_launch(void* const* d_in, const int* in_sizes, int n_in,
                              void* d_out, int out_size, void* d_ws, size_t ws_size,
                              hipStream_t stream) {
    const float* Q        = (const float*)d_in[0];
    const float* K        = (const float*)d_in[1];
    const float* V        = (const float*)d_in[2];
    const float* ref_mask = (const float*)d_in[3];
    const float* routing  = (const float*)d_in[4];
    float* out = (float*)d_out;

    const size_t elems = (size_t)NH * SEQ * DH;
    const size_t need  = 2 * elems * sizeof(short);

    if (ws_size < need) {
        dim3 grid(SEQ / 4, NH);
        anystory_attn_scalar<<<grid, 256, 0, stream>>>(Q, K, V, ref_mask, routing, out, 0);
        return;
    }

    short* Kb  = (short*)d_ws;
    short* Vtg = Kb + elems;

    cvt_k_kernel<<<(int)(elems / 4 / 256), 256, 0, stream>>>(K, Kb);
    cvt_v_kernel<<<dim3(198, NH), 256, 0, stream>>>(V, Vtg);

    attn_mfma<<<dim3(NH, 25), 512, 0, stream>>>(Q, Kb, Vtg, ref_mask, routing, out);

    // region 3 (router rows 3136..3167) via scalar kernel
    anystory_attn_scalar<<<dim3(8, NH), 256, 0, stream>>>(Q, K, V, ref_mask, routing, out, TRIR);
}

// Round 4
// 297.157 us; speedup vs baseline: 24.5796x; 1.2653x over previous
//
#include <hip/hip_runtime.h>
#include <hip/hip_bf16.h>

#define TXT   512
#define REDUX 64
#define IMG   2048
#define REFN  512
#define NC    2
#define SEQ   3168
#define DH    128
#define NH    24
#define TRE   576
#define TRI   2624
#define TRIR  3136
#define SCALE 0.08838834764831845f
#define L2E   1.4426950408889634f
#define QSC   (SCALE * L2E)          // scale folded with log2(e)
#define C100  (100.0f * L2E)         // 144.2695
#define CREF  (98.5f * L2E)          // 142.1055
#define THR2  (4.0f * L2E)           // defer-max threshold in log2 units

using f32x4  = __attribute__((ext_vector_type(4))) float;
using short8 = __attribute__((ext_vector_type(8))) short;

__device__ inline short f2bf(float x) {
    union { __hip_bfloat16 b; short s; } u;
    u.b = __float2bfloat16(x);
    return u.s;
}

__device__ inline void gload16(const short* g, short* l) {
    __builtin_amdgcn_global_load_lds(
        (const __attribute__((address_space(1))) unsigned int*)g,
        (__attribute__((address_space(3))) unsigned int*)l, 16, 0, 0);
}

// ---------------- pre-pass 1: K f32 -> bf16 linear ----------------
__global__ void cvt_k_kernel(const float* __restrict__ K, short* __restrict__ Kb) {
    const int i = blockIdx.x * 256 + threadIdx.x;
    const float4 v = ((const float4*)K)[i];
    short4 o;
    o.x = f2bf(v.x); o.y = f2bf(v.y); o.z = f2bf(v.z); o.w = f2bf(v.w);
    ((short4*)Kb)[i] = o;
}

// ---------------- pre-pass 2: V f32 -> bf16 transposed Vt[h][d][s] ----------------
__global__ void cvt_v_kernel(const float* __restrict__ V, short* __restrict__ Vt) {
    const int h  = blockIdx.y;
    const int s8 = blockIdx.x * 2 + (threadIdx.x >> 7);
    const int d  = threadIdx.x & 127;
    const int s0 = s8 * 8;
    const float* src = V + ((size_t)h * SEQ + s0) * DH + d;
    short8 w;
    #pragma unroll
    for (int j = 0; j < 8; ++j) w[j] = f2bf(src[j * DH]);
    short* dst = Vt + ((size_t)h * DH + d) * SEQ + s0;
    *(short8*)dst = w;
}

// ---------------- MFMA flash attention: all three regions ----------------
__global__ __launch_bounds__(256, 4)
void attn_mfma(const float* __restrict__ Q, const short* __restrict__ Kb,
               const short* __restrict__ Vtg, const float* __restrict__ ref_mask,
               const float* __restrict__ routing, float* __restrict__ out)
{
    __shared__ short Ks[64 * 128];     // [key][chunk^(key&7)] bf16
    __shared__ short Vs[128 * 64];     // [d][kc^(d&7)] bf16
    __shared__ short Pl[4][16 * 64];   // per-wave P, swizzled

    const int bid  = blockIdx.x;
    const int h    = bid % NH;         // same head -> same (bid%8) -> same XCD
    const int bx   = bid / NH;         // 0..49, heavy blocks dispatch first
    const int tid  = threadIdx.x;
    const int wave = tid >> 6, lane = tid & 63;
    const int g    = lane >> 4, l4 = lane & 15;

    int qbase, ks0 = 0, ntiles;
    bool masked = false, router = false;
    if (bx < 41)       { qbase = bx * 64; ntiles = 49; masked = true; }
    else if (bx == 41) { qbase = TRIR; ntiles = 33; router = true; }
    else {
        const int b2 = bx - 42;
        qbase = TRI + b2 * 64;
        ks0 = TRI + (b2 >> 2) * 256; ntiles = 4;
    }

    const int rbase = qbase + wave * 16;             // this wave's 16 q rows
    const bool valid = !(router && wave >= 2);

    // ---- staging address precompute (pre-swizzled global source, linear LDS dest) ----
    const short* KbH = Kb  + (size_t)h * SEQ * DH;
    const short* VtH = Vtg + (size_t)h * DH * SEQ;
    int koff[4], vD[4], vKC[4], voff[4];
    short *ksd[4], *vsd[4];
    #pragma unroll
    for (int j = 0; j < 4; ++j) {
        const int ci = tid + j * 256;
        const int kk = ci >> 4, kc = ci & 15;
        koff[j] = kk * 128 + ((kc ^ (kk & 7)) << 3);
        const int vd = ci >> 3, vk = ci & 7;
        vD[j] = vd; vKC[j] = vk;
        voff[j] = vd * SEQ + ((vk ^ (vd & 7)) << 3);
        ksd[j] = Ks + (size_t)(j * 256 + wave * 64) * 8;
        vsd[j] = Vs + (size_t)(j * 256 + wave * 64) * 8;
    }

    // ---- Q fragments (pre-scaled to log2 domain, bf16): row = l4, k-chunk = ks*4+g ----
    short8 qA[4];
    if (valid) {
        const int q = rbase + l4;
        const float* qp = Q + ((size_t)h * SEQ + q) * DH;
        #pragma unroll
        for (int ks = 0; ks < 4; ++ks) {
            const float4 a = *(const float4*)(qp + ks * 32 + g * 8);
            const float4 b = *(const float4*)(qp + ks * 32 + g * 8 + 4);
            short8 f;
            f[0] = f2bf(a.x * QSC); f[1] = f2bf(a.y * QSC);
            f[2] = f2bf(a.z * QSC); f[3] = f2bf(a.w * QSC);
            f[4] = f2bf(b.x * QSC); f[5] = f2bf(b.y * QSC);
            f[6] = f2bf(b.z * QSC); f[7] = f2bf(b.w * QSC);
            qA[ks] = f;
        }
    }

    f32x4 acc[8] = {};
    f32x4 m_run, l_run;
    #pragma unroll
    for (int r = 0; r < 4; ++r) { m_run[r] = -3.0e38f; l_run[r] = 0.f; }

    for (int t = 0; t < ntiles; ++t) {
        const int kt = masked ? t * 64
                     : (router ? (t < 32 ? TRE + t * 64 : TRIR) : ks0 + t * 64);
        const bool tail = router && (t == 32);       // only 32 of 64 keys valid
        __syncthreads();                             // previous tile consumed
        const short* kb = KbH + (size_t)kt * DH;
        const short* vb = VtH + kt;
        #pragma unroll
        for (int j = 0; j < 4; ++j) {
            const int ko = tail ? (koff[j] & (32 * 128 - 1)) : koff[j];
            gload16(kb + ko, ksd[j]);
        }
        #pragma unroll
        for (int j = 0; j < 4; ++j) {
            const int vo = tail ? (vD[j] * SEQ + (((vKC[j] ^ (vD[j] & 7)) & 3) << 3))
                                : voff[j];
            gload16(vb + vo, vsd[j]);
        }
        __syncthreads();                             // drains vmcnt + barrier

        if (!valid) continue;

        // ---- QK^T ----
        f32x4 s[4] = {};
        __builtin_amdgcn_s_setprio(1);
        #pragma unroll
        for (int nt = 0; nt < 4; ++nt) {
            const int key = nt * 16 + l4;
            #pragma unroll
            for (int ks = 0; ks < 4; ++ks) {
                const short8 kB = *(const short8*)(Ks + key * 128 + (((ks * 4 + g) ^ (key & 7)) << 3));
                s[nt] = __builtin_amdgcn_mfma_f32_16x16x32_bf16(qA[ks], kB, s[nt], 0, 0, 0);
            }
        }
        __builtin_amdgcn_s_setprio(0);

        // ---- masks (f32 exact, log2 domain) ----
        if (masked) {
            if (kt >= TRI) {                         // ref-key tiles
                const int cr = (kt - TRI) >> 8;
                const int q0 = rbase + g * 4;
                const bool hr = rbase >= TRE;
                f32x4 rt = {};
                if (hr) rt = *(const f32x4*)(routing + cr * IMG + (q0 - TRE));
                #pragma unroll
                for (int nt = 0; nt < 4; ++nt) {
                    const int j = kt - TRI + nt * 16 + l4;
                    const f32x4 rm = *(const f32x4*)(ref_mask + (size_t)j * TRI + q0);
                    #pragma unroll
                    for (int r = 0; r < 4; ++r) {
                        float add = rm[r] * C100 - CREF;          // (1.5+(rm-1)*100)*log2e
                        if (hr) add += rt[r] * C100 - C100;       // (rt-1)*100*log2e
                        s[nt][r] += add;
                    }
                }
            } else if (kt == TXT) {                  // redux-key tile
                if (rbase >= TRE) {
                    const int q0 = rbase + g * 4;
                    const f32x4 rt0 = *(const f32x4*)(routing + (q0 - TRE));
                    const f32x4 rt1 = *(const f32x4*)(routing + IMG + (q0 - TRE));
                    #pragma unroll
                    for (int nt = 0; nt < 4; ++nt)
                        #pragma unroll
                        for (int r = 0; r < 4; ++r)
                            s[nt][r] += (((nt >> 1) ? rt1[r] : rt0[r])) * C100 - C100;
                }
            }
        }
        if (tail) {                                  // router tail: keys >= SEQ invalid
            #pragma unroll
            for (int r = 0; r < 4; ++r) { s[2][r] = -3.0e38f; s[3][r] = -3.0e38f; }
        }

        // ---- online softmax (log2 domain) with defer-max ----
        f32x4 mx = s[0];
        #pragma unroll
        for (int nt = 1; nt < 4; ++nt)
            #pragma unroll
            for (int r = 0; r < 4; ++r) mx[r] = fmaxf(mx[r], s[nt][r]);
        #pragma unroll
        for (int dd = 1; dd < 16; dd <<= 1)
            #pragma unroll
            for (int r = 0; r < 4; ++r) mx[r] = fmaxf(mx[r], __shfl_xor(mx[r], dd));

        float gmax = fmaxf(fmaxf(mx[0] - m_run[0], mx[1] - m_run[1]),
                           fmaxf(mx[2] - m_run[2], mx[3] - m_run[3]));
        if (__any(gmax > THR2)) {
            f32x4 corr;
            #pragma unroll
            for (int r = 0; r < 4; ++r) {
                const float mn = fmaxf(m_run[r], mx[r]);
                corr[r] = exp2f(m_run[r] - mn);
                m_run[r] = mn;
                l_run[r] *= corr[r];
            }
            #pragma unroll
            for (int nt = 0; nt < 8; ++nt)
                #pragma unroll
                for (int r = 0; r < 4; ++r) acc[nt][r] *= corr[r];
        }

        f32x4 rs = {};
        #pragma unroll
        for (int nt = 0; nt < 4; ++nt)
            #pragma unroll
            for (int r = 0; r < 4; ++r) {
                s[nt][r] = exp2f(s[nt][r] - m_run[r]);
                rs[r] += s[nt][r];
            }
        #pragma unroll
        for (int dd = 1; dd < 16; dd <<= 1)
            #pragma unroll
            for (int r = 0; r < 4; ++r) rs[r] += __shfl_xor(rs[r], dd);
        #pragma unroll
        for (int r = 0; r < 4; ++r) l_run[r] += rs[r];

        // ---- P (C/D layout) -> swizzled LDS ----
        #pragma unroll
        for (int nt = 0; nt < 4; ++nt)
            #pragma unroll
            for (int r = 0; r < 4; ++r) {
                const int row = g * 4 + r;
                const int col = nt * 16 + l4;
                Pl[wave][row * 64 + (col ^ ((row & 7) << 3))] = f2bf(s[nt][r]);
            }

        // ---- PV ----
        __builtin_amdgcn_s_setprio(1);
        #pragma unroll
        for (int ks2 = 0; ks2 < 2; ++ks2) {
            const short8 pA = *(const short8*)(&Pl[wave][l4 * 64 + (((ks2 * 4 + g) ^ (l4 & 7)) << 3)]);
            #pragma unroll
            for (int nt = 0; nt < 8; ++nt) {
                const int d = nt * 16 + l4;
                const short8 vB = *(const short8*)(Vs + d * 64 + (((ks2 * 4 + g) ^ (d & 7)) << 3));
                acc[nt] = __builtin_amdgcn_mfma_f32_16x16x32_bf16(pA, vB, acc[nt], 0, 0, 0);
            }
        }
        __builtin_amdgcn_s_setprio(0);
    }

    if (valid) {
        #pragma unroll
        for (int nt = 0; nt < 8; ++nt)
            #pragma unroll
            for (int r = 0; r < 4; ++r) {
                const int q = rbase + g * 4 + r;
                out[((size_t)h * SEQ + q) * DH + nt * 16 + l4] = acc[nt][r] / l_run[r];
            }
    }
}

// ---------------- scalar kernel (full fallback only) ----------------
#define KT  32
#define LDK (DH + 4)
__global__ __launch_bounds__(256, 2)
void anystory_attn_scalar(const float* __restrict__ Q, const float* __restrict__ K,
                          const float* __restrict__ V, const float* __restrict__ ref_mask,
                          const float* __restrict__ routing, float* __restrict__ out, int row0)
{
    __shared__ float KsS[KT][LDK];
    __shared__ float VsS[KT][LDK];

    const int h    = blockIdx.y;
    const int r0   = row0 + blockIdx.x * 4;
    const int tid  = threadIdx.x;
    const int wave = tid >> 6;
    const int lane = tid & 63;
    const int key_l = lane & 31;
    const int half  = lane >> 5;
    const int row  = r0 + wave;

    int rs0, re0, rs1 = 0, re1 = 0;
    bool masked = false;
    if (r0 < TRI) { rs0 = 0; re0 = TRIR; masked = true; }
    else if (r0 < TRIR) {
        int c = (r0 - TRI) / (REFN / NC);
        rs0 = TRI + c * (REFN / NC); re0 = rs0 + (REFN / NC);
    } else { rs0 = TRE; re0 = TRI; rs1 = TRIR; re1 = SEQ; }

    float4 qreg[16];
    const float4* qptr = (const float4*)(Q + ((size_t)h * SEQ + row) * DH + half * 64);
    #pragma unroll
    for (int i = 0; i < 16; ++i) qreg[i] = qptr[i];

    float m = -1e30f, l = 0.f, acc0 = 0.f, acc1 = 0.f;

    for (int range = 0; range < 2; ++range) {
        const int ks = (range == 0) ? rs0 : rs1;
        const int ke = (range == 0) ? re0 : re1;
        for (int kt = ks; kt < ke; kt += KT) {
            __syncthreads();
            #pragma unroll
            for (int i = 0; i < 4; ++i) {
                int idx = tid + i * 256;
                int rr = idx >> 5, cc = (idx & 31) * 4;
                const float4 kv = ((const float4*)(K + ((size_t)h * SEQ + kt + rr) * DH))[idx & 31];
                const float4 vv = ((const float4*)(V + ((size_t)h * SEQ + kt + rr) * DH))[idx & 31];
                *(float4*)&KsS[rr][cc] = kv;
                *(float4*)&VsS[rr][cc] = vv;
            }
            __syncthreads();

            const int kglob = kt + key_l;
            float dot = 0.f;
            #pragma unroll
            for (int i = 0; i < 16; ++i) {
                float4 k4 = *(const float4*)&KsS[key_l][half * 64 + i * 4];
                dot += qreg[i].x * k4.x + qreg[i].y * k4.y + qreg[i].z * k4.z + qreg[i].w * k4.w;
            }
            dot += __shfl_xor(dot, 32);
            float logit = dot * SCALE;

            if (masked) {
                if (kglob >= TRI) {
                    logit += 1.5f + (ref_mask[(size_t)(kglob - TRI) * TRI + row] - 1.f) * 100.f;
                    if (row >= TRE)
                        logit += (routing[((kglob - TRI) >> 8) * IMG + (row - TRE)] - 1.f) * 100.f;
                } else if (kglob >= TXT && kglob < TRE && row >= TRE) {
                    logit += (routing[((kglob - TXT) >> 5) * IMG + (row - TRE)] - 1.f) * 100.f;
                }
            }

            float tm = logit;
            tm = fmaxf(tm, __shfl_xor(tm, 1));
            tm = fmaxf(tm, __shfl_xor(tm, 2));
            tm = fmaxf(tm, __shfl_xor(tm, 4));
            tm = fmaxf(tm, __shfl_xor(tm, 8));
            tm = fmaxf(tm, __shfl_xor(tm, 16));
            const float nm   = fmaxf(m, tm);
            const float corr = __expf(m - nm);
            const float p    = __expf(logit - nm);
            float ps = p;
            ps += __shfl_xor(ps, 1);
            ps += __shfl_xor(ps, 2);
            ps += __shfl_xor(ps, 4);
            ps += __shfl_xor(ps, 8);
            ps += __shfl_xor(ps, 16);
            l = l * corr + ps;
            acc0 *= corr; acc1 *= corr;
            m = nm;

            #pragma unroll
            for (int k = 0; k < KT; ++k) {
                const float pk = __shfl(p, k);
                acc0 += pk * VsS[k][lane];
                acc1 += pk * VsS[k][lane + 64];
            }
        }
    }

    const float inv = 1.f / l;
    float* op = out + ((size_t)h * SEQ + row) * DH;
    op[lane]      = acc0 * inv;
    op[lane + 64] = acc1 * inv;
}

extern "C" void kernel_launch(void* const* d_in, const int* in_sizes, int n_in,
                              void* d_out, int out_size, void* d_ws, size_t ws_size,
                              hipStream_t stream) {
    const float* Q        = (const float*)d_in[0];
    const float* K        = (const float*)d_in[1];
    const float* V        = (const float*)d_in[2];
    const float* ref_mask = (const float*)d_in[3];
    const float* routing  = (const float*)d_in[4];
    float* out = (float*)d_out;

    const size_t elems = (size_t)NH * SEQ * DH;
    const size_t need  = 2 * elems * sizeof(short);

    if (ws_size < need) {
        dim3 grid(SEQ / 4, NH);
        anystory_attn_scalar<<<grid, 256, 0, stream>>>(Q, K, V, ref_mask, routing, out, 0);
        return;
    }

    short* Kb  = (short*)d_ws;
    short* Vtg = Kb + elems;

    cvt_k_kernel<<<(int)(elems / 4 / 256), 256, 0, stream>>>(K, Kb);
    cvt_v_kernel<<<dim3(198, NH), 256, 0, stream>>>(V, Vtg);

    // 50 block-cols per head (41 heavy, 1 router, 8 ref), head-major for XCD L2 locality
    attn_mfma<<<dim3(NH * 50), 256, 0, stream>>>(Q, Kb, Vtg, ref_mask, routing, out);
}